// Round 2
// baseline (339.703 us; speedup 1.0000x reference)
//
#include <hip/hip_runtime.h>
#include <hip/hip_bf16.h>
#include <math.h>

#define BB 8
#define LL 4096
#define DD 768
#define NN 16
#define RR 8
#define MROWS (BB*LL)       // 32768 rows
#define KAUG 800            // 768 (x) + 16 (hs) + 16 (zero pad)
#define CCH 64              // chunk length for scan
#define NCH (LL/CCH)        // 64 chunks per batch

typedef unsigned int u32;
typedef unsigned short u16;
typedef __attribute__((ext_vector_type(8))) short short8;
typedef __attribute__((ext_vector_type(4))) float f32x4;
typedef __attribute__((ext_vector_type(4))) unsigned short us4;

__device__ __forceinline__ u16 f2bf(float f) {
  u32 u = __float_as_uint(f);
  u32 r = (u + 0x7fffu + ((u >> 16) & 1u)) >> 16;  // RNE
  return (u16)r;
}

__device__ __forceinline__ void gload_lds16(const void* g, void* l) {
  __builtin_amdgcn_global_load_lds(
      (const __attribute__((address_space(1))) u32*)g,
      (__attribute__((address_space(3))) u32*)l, 16, 0, 0);
}

// ---------------- K0a: M = diag(sigmoid(a)) + V U^T ; MC = M^64 ; bsum ----
__global__ void k_prep(const float* __restrict__ a_logit, const float* __restrict__ U,
                       const float* __restrict__ V, const float* __restrict__ b_out,
                       const float* __restrict__ b_skip,
                       float* __restrict__ Mw, float* __restrict__ MCw,
                       float* __restrict__ bsum) {
  __shared__ float cur[256];
  __shared__ float nxt[256];
  int t = threadIdx.x;
  int m = t >> 4, n = t & 15;
  float s = 0.f;
  #pragma unroll
  for (int r = 0; r < RR; r++) s += V[m*RR+r] * U[n*RR+r];
  if (m == n) s += 1.f / (1.f + expf(-a_logit[n]));
  cur[t] = s;
  Mw[t] = s;
  __syncthreads();
  // MC = M^64 : 6 squarings
  for (int it = 0; it < 6; ++it) {
    float acc = 0.f;
    #pragma unroll
    for (int k = 0; k < 16; k++) acc += cur[m*16+k] * cur[k*16+n];
    nxt[t] = acc;
    __syncthreads();
    cur[t] = nxt[t];
    __syncthreads();
  }
  MCw[t] = cur[t];
  for (int d = t; d < DD; d += 256) bsum[d] = b_out[d] + b_skip[d];
}

// ---------------- K0b: Waug = [W_skip | W_out | 0] bf16 ; WinG = [W_in;W_gate] bf16
__global__ void k_weights(const float* __restrict__ W_skip, const float* __restrict__ W_out,
                          const float* __restrict__ W_in, const float* __restrict__ W_gate,
                          u16* __restrict__ Waug, u16* __restrict__ WinG) {
  int bid = blockIdx.x;
  int t = threadIdx.x;
  if (bid < DD) {
    int d = bid;
    for (int c = t; c < KAUG; c += 256) {
      float v;
      if (c < DD)           v = W_skip[d*DD + c];
      else if (c < DD+NN)   v = W_out[d*NN + (c-DD)];
      else                  v = 0.f;
      Waug[d*KAUG + c] = f2bf(v);
    }
  } else {
    int r = bid - DD;  // 0..31
    const float* Wsrc = (r < NN) ? (W_in + r*DD) : (W_gate + (r-NN)*DD);
    for (int c = t; c < DD; c += 256) WinG[r*DD + c] = f2bf(Wsrc[c]);
  }
}

// ---------------- K1: x fp32 -> Xaug[:, 0:768] bf16 ; zero Xaug[:, 784:800]
__global__ void k_convert(const float* __restrict__ x, u16* __restrict__ Xaug) {
  const long total4 = (long)MROWS * (DD/4);
  const int stride = gridDim.x * blockDim.x;
  for (long i = (long)blockIdx.x*blockDim.x + threadIdx.x; i < total4; i += stride) {
    long row = i / (DD/4);
    int  c4  = (int)(i - row*(DD/4));
    float4 v = ((const float4*)x)[i];
    us4 o;
    o.x = f2bf(v.x); o.y = f2bf(v.y); o.z = f2bf(v.z); o.w = f2bf(v.w);
    *(us4*)(Xaug + row*KAUG + c4*4) = o;
  }
  const long totalz = (long)MROWS * 4;
  for (long i = (long)blockIdx.x*blockDim.x + threadIdx.x; i < totalz; i += stride) {
    long row = i >> 2; int q = (int)(i & 3);
    us4 z = (us4)0;
    *(us4*)(Xaug + row*KAUG + 784 + q*4) = z;
  }
}

// ---------------- K2: gu = sigmoid(x@Wg^T + bg) * (x@Wi^T + bi)  (MFMA, N=32 cols)
__global__ __launch_bounds__(256) void k_gu(const u16* __restrict__ Xaug,
                                            const u16* __restrict__ WinG,
                                            const float* __restrict__ b_in,
                                            const float* __restrict__ b_gate,
                                            float* __restrict__ gu) {
  __shared__ u16 At[128*32];
  __shared__ u16 Bt[32*32];
  int tid = threadIdx.x;
  int wave = tid >> 6, lane = tid & 63;
  int rowbase = blockIdx.x * 128;
  f32x4 acc[2][2] = {};
  for (int it = 0; it < DD/32; ++it) {
    int k0 = it * 32;
    #pragma unroll
    for (int p = 0; p < 2; p++) {
      int c = tid + p*256;
      int r = c >> 2, co = c & 3;
      gload_lds16(Xaug + (long)(rowbase + r)*KAUG + k0 + co*8, At + c*8);
    }
    if (tid < 128) {
      int r = tid >> 2, co = tid & 3;
      gload_lds16(WinG + r*DD + k0 + co*8, Bt + tid*8);
    }
    __syncthreads();
    int l15 = lane & 15, lh = lane >> 4;
    short8 a[2], b[2];
    #pragma unroll
    for (int i = 0; i < 2; i++)
      a[i] = *(const short8*)(At + (wave*32 + i*16 + l15)*32 + lh*8);
    #pragma unroll
    for (int j = 0; j < 2; j++)
      b[j] = *(const short8*)(Bt + (j*16 + l15)*32 + lh*8);
    #pragma unroll
    for (int i = 0; i < 2; i++)
      #pragma unroll
      for (int j = 0; j < 2; j++)
        acc[i][j] = __builtin_amdgcn_mfma_f32_16x16x32_bf16(a[i], b[j], acc[i][j], 0, 0, 0);
    __syncthreads();
  }
  int l15 = lane & 15, lh = lane >> 4;
  float bi = b_in[l15], bg = b_gate[l15];
  #pragma unroll
  for (int i = 0; i < 2; i++)
    #pragma unroll
    for (int r = 0; r < 4; r++) {
      int row = rowbase + wave*32 + i*16 + lh*4 + r;
      float u = acc[i][0][r] + bi;
      float g = 1.f / (1.f + __expf(-(acc[i][1][r] + bg)));
      gu[(long)row*NN + l15] = g * u;
    }
}

// ---------------- K4: per-chunk local scan from zero -> cend
__global__ void k_scan_local(const float* __restrict__ gu, const float* __restrict__ Mw,
                             float* __restrict__ cend) {
  int lane = threadIdx.x & 63;
  int grp = lane >> 4, n = lane & 15;
  int cid = blockIdx.x*4 + grp;      // 0..511
  int b = cid >> 6, k = cid & 63;
  float Mcol[16];
  #pragma unroll
  for (int m = 0; m < 16; m++) Mcol[m] = Mw[m*16 + n];
  float h = 0.f;
  const float* g = gu + ((long)(b*LL) + k*CCH)*NN + n;
  for (int t = 0; t < CCH; t++) {
    float hn = g[(long)t*NN];
    #pragma unroll
    for (int m = 0; m < 16; m++) hn += __shfl(h, m, 16) * Mcol[m];
    h = hn;
  }
  cend[(b*NCH + k)*NN + n] = h;
}

// ---------------- K5: chunk prefix: Hstart[b][k] = state before chunk k
__global__ void k_scan_prefix(const float* __restrict__ cend, const float* __restrict__ MCw,
                              float* __restrict__ Hstart) {
  int t = threadIdx.x;     // 0..127
  int b = t >> 4, n = t & 15;
  float Mcol[16];
  #pragma unroll
  for (int m = 0; m < 16; m++) Mcol[m] = MCw[m*16 + n];
  float h = 0.f;
  for (int k = 0; k < NCH; k++) {
    Hstart[(b*NCH + k)*NN + n] = h;
    float hn = cend[(b*NCH + k)*NN + n];
    #pragma unroll
    for (int m = 0; m < 16; m++) hn += __shfl(h, m, 16) * Mcol[m];
    h = hn;
  }
}

// ---------------- K6: chunk final scan -> hs bf16 into Xaug[:, 768:784]
__global__ void k_scan_final(const float* __restrict__ gu, const float* __restrict__ Mw,
                             const float* __restrict__ Hstart, u16* __restrict__ Xaug) {
  int lane = threadIdx.x & 63;
  int grp = lane >> 4, n = lane & 15;
  int cid = blockIdx.x*4 + grp;
  int b = cid >> 6, k = cid & 63;
  float Mcol[16];
  #pragma unroll
  for (int m = 0; m < 16; m++) Mcol[m] = Mw[m*16 + n];
  float h = Hstart[(b*NCH + k)*NN + n];
  const float* g = gu + ((long)(b*LL) + k*CCH)*NN + n;
  u16* xa = Xaug + ((long)(b*LL) + k*CCH)*KAUG + DD + n;
  for (int t = 0; t < CCH; t++) {
    float hn = g[(long)t*NN];
    #pragma unroll
    for (int m = 0; m < 16; m++) hn += __shfl(h, m, 16) * Mcol[m];
    h = hn;
    xa[(long)t*KAUG] = f2bf(h);
  }
}

// ---------------- K7: y = Xaug @ Waug^T + bsum   (M=32768, N=768, K=800)
__global__ __launch_bounds__(256) void k_out(const u16* __restrict__ Xaug,
                                             const u16* __restrict__ Waug,
                                             const float* __restrict__ bsum,
                                             float* __restrict__ y) {
  __shared__ u16 At[128*32];
  __shared__ u16 Bt[128*32];
  int tid = threadIdx.x;
  int wave = tid >> 6, lane = tid & 63;
  int wm = wave >> 1, wn = wave & 1;
  int rowbase = blockIdx.x * 128;
  int colbase = blockIdx.y * 128;
  f32x4 acc[4][4] = {};
  for (int it = 0; it < KAUG/32; ++it) {
    int k0 = it * 32;
    #pragma unroll
    for (int p = 0; p < 2; p++) {
      int c = tid + p*256;
      int r = c >> 2, co = c & 3;
      gload_lds16(Xaug + (long)(rowbase + r)*KAUG + k0 + co*8, At + c*8);
      gload_lds16(Waug + (long)(colbase + r)*KAUG + k0 + co*8, Bt + c*8);
    }
    __syncthreads();
    int l15 = lane & 15, lh = lane >> 4;
    short8 a[4], b[4];
    #pragma unroll
    for (int i = 0; i < 4; i++)
      a[i] = *(const short8*)(At + (wm*64 + i*16 + l15)*32 + lh*8);
    #pragma unroll
    for (int j = 0; j < 4; j++)
      b[j] = *(const short8*)(Bt + (wn*64 + j*16 + l15)*32 + lh*8);
    #pragma unroll
    for (int i = 0; i < 4; i++)
      #pragma unroll
      for (int j = 0; j < 4; j++)
        acc[i][j] = __builtin_amdgcn_mfma_f32_16x16x32_bf16(a[i], b[j], acc[i][j], 0, 0, 0);
    __syncthreads();
  }
  int l15 = lane & 15, lh = lane >> 4;
  #pragma unroll
  for (int j = 0; j < 4; j++) {
    int col = colbase + wn*64 + j*16 + l15;
    float bs = bsum[col];
    #pragma unroll
    for (int i = 0; i < 4; i++) {
      int row0 = rowbase + wm*64 + i*16 + lh*4;
      #pragma unroll
      for (int r = 0; r < 4; r++)
        y[(long)(row0 + r)*DD + col] = acc[i][j][r] + bs;
    }
  }
}

extern "C" void kernel_launch(void* const* d_in, const int* in_sizes, int n_in,
                              void* d_out, int out_size, void* d_ws, size_t ws_size,
                              hipStream_t stream) {
  (void)in_sizes; (void)n_in; (void)out_size; (void)ws_size;
  const float* x       = (const float*)d_in[0];
  const float* a_logit = (const float*)d_in[1];
  const float* U       = (const float*)d_in[2];
  const float* V       = (const float*)d_in[3];
  const float* W_in    = (const float*)d_in[4];
  const float* b_in    = (const float*)d_in[5];
  const float* W_gate  = (const float*)d_in[6];
  const float* b_gate  = (const float*)d_in[7];
  const float* W_out   = (const float*)d_in[8];
  const float* b_out   = (const float*)d_in[9];
  const float* W_skip  = (const float*)d_in[10];
  const float* b_skip  = (const float*)d_in[11];

  char* ws = (char*)d_ws;
  u16*   Xaug = (u16*)(ws + 0);            // 52,428,800 B
  u16*   Waug = (u16*)(ws + 52428800);     //  1,228,800 B
  u16*   WinG = (u16*)(ws + 53657600);     //     49,152 B
  float* gu   = (float*)(ws + 53706752);   //  2,097,152 B
  float* Mw   = (float*)(ws + 55803904);   //      1,024 B
  float* MCw  = (float*)(ws + 55804928);   //      1,024 B
  float* cend = (float*)(ws + 55805952);   //     32,768 B
  float* Hst  = (float*)(ws + 55838720);   //     32,768 B
  float* bsum = (float*)(ws + 55871488);   //      3,072 B
  float* y    = (float*)d_out;

  hipLaunchKernelGGL(k_prep,        dim3(1),      dim3(256), 0, stream,
                     a_logit, U, V, b_out, b_skip, Mw, MCw, bsum);
  hipLaunchKernelGGL(k_weights,     dim3(800),    dim3(256), 0, stream,
                     W_skip, W_out, W_in, W_gate, Waug, WinG);
  hipLaunchKernelGGL(k_convert,     dim3(2048),   dim3(256), 0, stream, x, Xaug);
  hipLaunchKernelGGL(k_gu,          dim3(256),    dim3(256), 0, stream,
                     Xaug, WinG, b_in, b_gate, gu);
  hipLaunchKernelGGL(k_scan_local,  dim3(128),    dim3(64),  0, stream, gu, Mw, cend);
  hipLaunchKernelGGL(k_scan_prefix, dim3(1),      dim3(128), 0, stream, cend, MCw, Hst);
  hipLaunchKernelGGL(k_scan_final,  dim3(128),    dim3(64),  0, stream, gu, Mw, Hst, Xaug);
  hipLaunchKernelGGL(k_out,         dim3(256, 6), dim3(256), 0, stream,
                     Xaug, Waug, bsum, y);
}

// Round 4
// 334.162 us; speedup vs baseline: 1.0166x; 1.0166x over previous
//
#include <hip/hip_runtime.h>
#include <hip/hip_bf16.h>
#include <math.h>

#define BB 8
#define LL 4096
#define DD 768
#define NN 16
#define RR 8
#define MROWS (BB*LL)       // 32768 rows
#define KAUG 800            // 768 (x) + 16 (hs) + 16 (zero pad)
#define CCH 64              // chunk length for scan
#define NCH (LL/CCH)        // 64 chunks per batch

typedef unsigned int u32;
typedef unsigned short u16;
typedef __attribute__((ext_vector_type(8))) short short8;
typedef __attribute__((ext_vector_type(4))) float f32x4;
typedef __attribute__((ext_vector_type(4))) unsigned short us4;

__device__ __forceinline__ u16 f2bf(float f) {
  u32 u = __float_as_uint(f);
  u32 r = (u + 0x7fffu + ((u >> 16) & 1u)) >> 16;  // RNE
  return (u16)r;
}

__device__ __forceinline__ void gload_lds16(const void* g, void* l) {
  __builtin_amdgcn_global_load_lds(
      (const __attribute__((address_space(1))) u32*)g,
      (__attribute__((address_space(3))) u32*)l, 16, 0, 0);
}

// ---------------- K0a: M = diag(sigmoid(a)) + V U^T ; MC = M^64 ; bsum ----
__global__ void k_prep(const float* __restrict__ a_logit, const float* __restrict__ U,
                       const float* __restrict__ V, const float* __restrict__ b_out,
                       const float* __restrict__ b_skip,
                       float* __restrict__ Mw, float* __restrict__ MCw,
                       float* __restrict__ bsum) {
  __shared__ float cur[256];
  __shared__ float nxt[256];
  int t = threadIdx.x;
  int m = t >> 4, n = t & 15;
  float s = 0.f;
  #pragma unroll
  for (int r = 0; r < RR; r++) s += V[m*RR+r] * U[n*RR+r];
  if (m == n) s += 1.f / (1.f + expf(-a_logit[n]));
  cur[t] = s;
  Mw[t] = s;
  __syncthreads();
  // MC = M^64 : 6 squarings
  for (int it = 0; it < 6; ++it) {
    float acc = 0.f;
    #pragma unroll
    for (int k = 0; k < 16; k++) acc += cur[m*16+k] * cur[k*16+n];
    nxt[t] = acc;
    __syncthreads();
    cur[t] = nxt[t];
    __syncthreads();
  }
  MCw[t] = cur[t];
  for (int d = t; d < DD; d += 256) bsum[d] = b_out[d] + b_skip[d];
}

// ---------------- K0b: Waug = [W_skip | W_out | 0] bf16 ; WinG = [W_in;W_gate] bf16
__global__ void k_weights(const float* __restrict__ W_skip, const float* __restrict__ W_out,
                          const float* __restrict__ W_in, const float* __restrict__ W_gate,
                          u16* __restrict__ Waug, u16* __restrict__ WinG) {
  int bid = blockIdx.x;
  int t = threadIdx.x;
  if (bid < DD) {
    int d = bid;
    for (int c = t; c < KAUG; c += 256) {
      float v;
      if (c < DD)           v = W_skip[d*DD + c];
      else if (c < DD+NN)   v = W_out[d*NN + (c-DD)];
      else                  v = 0.f;
      Waug[d*KAUG + c] = f2bf(v);
    }
  } else {
    int r = bid - DD;  // 0..31
    const float* Wsrc = (r < NN) ? (W_in + r*DD) : (W_gate + (r-NN)*DD);
    for (int c = t; c < DD; c += 256) WinG[r*DD + c] = f2bf(Wsrc[c]);
  }
}

// ---------------- K1: x fp32 -> Xaug[:, 0:768] bf16 ; zero Xaug[:, 784:800]
// div-free: 4 rows per block (one per wave), 8192 blocks
__global__ void k_convert(const float* __restrict__ x, u16* __restrict__ Xaug) {
  int row  = blockIdx.x * 4 + (threadIdx.x >> 6);
  int lane = threadIdx.x & 63;
  const float4* xr = (const float4*)(x + (long)row * DD);
  u16* xo = Xaug + (long)row * KAUG;
  #pragma unroll
  for (int p = 0; p < 3; p++) {
    int c4 = lane + p*64;          // 0..191
    float4 v = xr[c4];
    us4 o;
    o.x = f2bf(v.x); o.y = f2bf(v.y); o.z = f2bf(v.z); o.w = f2bf(v.w);
    *(us4*)(xo + c4*4) = o;
  }
  if (lane < 4) *(us4*)(xo + 784 + lane*4) = (us4)0;
}

// ---------------- K2: gu = sigmoid(x@Wg^T + bg) * (x@Wi^T + bi)  (MFMA, N=32 cols)
// writes gu TRANSPOSED: gu_T[(b*16+n)*4096 + t]  (contiguous in t for the scans)
__global__ __launch_bounds__(256) void k_gu(const u16* __restrict__ Xaug,
                                            const u16* __restrict__ WinG,
                                            const float* __restrict__ b_in,
                                            const float* __restrict__ b_gate,
                                            float* __restrict__ gu_T) {
  __shared__ u16 At[128*32];
  __shared__ u16 Bt[32*32];
  int tid = threadIdx.x;
  int wave = tid >> 6, lane = tid & 63;
  int rowbase = blockIdx.x * 128;
  f32x4 acc[2][2] = {};
  for (int it = 0; it < DD/32; ++it) {
    int k0 = it * 32;
    #pragma unroll
    for (int p = 0; p < 2; p++) {
      int c = tid + p*256;
      int r = c >> 2, co = c & 3;
      gload_lds16(Xaug + (long)(rowbase + r)*KAUG + k0 + co*8, At + c*8);
    }
    if (tid < 128) {
      int r = tid >> 2, co = tid & 3;
      gload_lds16(WinG + r*DD + k0 + co*8, Bt + tid*8);
    }
    __syncthreads();
    int l15 = lane & 15, lh = lane >> 4;
    short8 a[2], b[2];
    #pragma unroll
    for (int i = 0; i < 2; i++)
      a[i] = *(const short8*)(At + (wave*32 + i*16 + l15)*32 + lh*8);
    #pragma unroll
    for (int j = 0; j < 2; j++)
      b[j] = *(const short8*)(Bt + (j*16 + l15)*32 + lh*8);
    #pragma unroll
    for (int i = 0; i < 2; i++)
      #pragma unroll
      for (int j = 0; j < 2; j++)
        acc[i][j] = __builtin_amdgcn_mfma_f32_16x16x32_bf16(a[i], b[j], acc[i][j], 0, 0, 0);
    __syncthreads();
  }
  int l15 = lane & 15, lh = lane >> 4;
  float bi = b_in[l15], bg = b_gate[l15];
  #pragma unroll
  for (int i = 0; i < 2; i++) {
    int row0 = rowbase + wave*32 + i*16 + lh*4;   // 4 consecutive rows (same b)
    int b = row0 >> 12;
    int t0 = row0 & 4095;
    float4 o;
    {
      float u0 = acc[i][0][0] + bi, u1 = acc[i][0][1] + bi;
      float u2 = acc[i][0][2] + bi, u3 = acc[i][0][3] + bi;
      float g0 = 1.f/(1.f+__expf(-(acc[i][1][0]+bg)));
      float g1 = 1.f/(1.f+__expf(-(acc[i][1][1]+bg)));
      float g2 = 1.f/(1.f+__expf(-(acc[i][1][2]+bg)));
      float g3 = 1.f/(1.f+__expf(-(acc[i][1][3]+bg)));
      o.x = g0*u0; o.y = g1*u1; o.z = g2*u2; o.w = g3*u3;
    }
    *(float4*)(gu_T + ((long)(b*16 + l15) << 12) + t0) = o;
  }
}

// ---------------- K4: per-chunk local scan from zero -> cend
// gu_T layout: lane n reads a contiguous 256B stream; preload whole chunk to regs
__global__ void k_scan_local(const float* __restrict__ gu_T, const float* __restrict__ Mw,
                             float* __restrict__ cend) {
  int lane = threadIdx.x & 63;
  int grp = lane >> 4, n = lane & 15;
  int cid = blockIdx.x*4 + grp;      // 0..511
  int b = cid >> 6, k = cid & 63;
  float Mcol[16];
  #pragma unroll
  for (int m = 0; m < 16; m++) Mcol[m] = Mw[m*16 + n];
  const float4* g4 = (const float4*)(gu_T + ((long)(b*16 + n) << 12) + k*CCH);
  float gv[CCH];
  #pragma unroll
  for (int q = 0; q < CCH/4; q++) {
    float4 v = g4[q];
    gv[q*4+0]=v.x; gv[q*4+1]=v.y; gv[q*4+2]=v.z; gv[q*4+3]=v.w;
  }
  float h = 0.f;
  #pragma unroll
  for (int t = 0; t < CCH; t++) {
    float hn = gv[t];
    #pragma unroll
    for (int m = 0; m < 16; m++) hn += __shfl(h, m, 16) * Mcol[m];
    h = hn;
  }
  cend[(b*NCH + k)*NN + n] = h;
}

// ---------------- K5: chunk prefix: Hstart[b][k] = state before chunk k (LDS-staged)
__global__ void k_scan_prefix(const float* __restrict__ cend, const float* __restrict__ MCw,
                              float* __restrict__ Hstart) {
  __shared__ float s[BB*NCH*NN];   // 8192 floats = 32 KB
  int t = threadIdx.x;             // 256 threads
  for (int i = t; i < BB*NCH*NN; i += 256) s[i] = cend[i];
  __syncthreads();
  if (t < 128) {
    int b = t >> 4, n = t & 15;
    float Mcol[16];
    #pragma unroll
    for (int m = 0; m < 16; m++) Mcol[m] = MCw[m*16 + n];
    float h = 0.f;
    for (int k = 0; k < NCH; k++) {
      Hstart[(b*NCH + k)*NN + n] = h;
      float hn = s[(b*NCH + k)*NN + n];
      #pragma unroll
      for (int m = 0; m < 16; m++) hn += __shfl(h, m, 16) * Mcol[m];
      h = hn;
    }
  }
}

// ---------------- K6: chunk final scan -> hs bf16 into Xaug[:, 768:784]
__global__ void k_scan_final(const float* __restrict__ gu_T, const float* __restrict__ Mw,
                             const float* __restrict__ Hstart, u16* __restrict__ Xaug) {
  int lane = threadIdx.x & 63;
  int grp = lane >> 4, n = lane & 15;
  int cid = blockIdx.x*4 + grp;
  int b = cid >> 6, k = cid & 63;
  float Mcol[16];
  #pragma unroll
  for (int m = 0; m < 16; m++) Mcol[m] = Mw[m*16 + n];
  const float4* g4 = (const float4*)(gu_T + ((long)(b*16 + n) << 12) + k*CCH);
  float gv[CCH];
  #pragma unroll
  for (int q = 0; q < CCH/4; q++) {
    float4 v = g4[q];
    gv[q*4+0]=v.x; gv[q*4+1]=v.y; gv[q*4+2]=v.z; gv[q*4+3]=v.w;
  }
  float h = Hstart[(b*NCH + k)*NN + n];
  u16* xa = Xaug + ((long)(b*LL) + k*CCH)*KAUG + DD + n;
  #pragma unroll
  for (int t = 0; t < CCH; t++) {
    float hn = gv[t];
    #pragma unroll
    for (int m = 0; m < 16; m++) hn += __shfl(h, m, 16) * Mcol[m];
    h = hn;
    xa[(long)t*KAUG] = f2bf(h);
  }
}

// ---------------- K7: y = Xaug @ Waug^T + bsum   (M=32768, N=768, K=800)
__global__ __launch_bounds__(256) void k_out(const u16* __restrict__ Xaug,
                                             const u16* __restrict__ Waug,
                                             const float* __restrict__ bsum,
                                             float* __restrict__ y) {
  __shared__ u16 At[128*32];
  __shared__ u16 Bt[128*32];
  int tid = threadIdx.x;
  int wave = tid >> 6, lane = tid & 63;
  int wm = wave >> 1, wn = wave & 1;
  // bijective XCD swizzle: grid 1536 linear, 1536 % 8 == 0
  int bid = blockIdx.x;
  int swz = (bid & 7) * 192 + (bid >> 3);
  int rowbase = (swz & 255) * 128;
  int colbase = (swz >> 8) * 128;
  f32x4 acc[4][4] = {};
  for (int it = 0; it < KAUG/32; ++it) {
    int k0 = it * 32;
    #pragma unroll
    for (int p = 0; p < 2; p++) {
      int c = tid + p*256;
      int r = c >> 2, co = c & 3;
      gload_lds16(Xaug + (long)(rowbase + r)*KAUG + k0 + co*8, At + c*8);
      gload_lds16(Waug + (long)(colbase + r)*KAUG + k0 + co*8, Bt + c*8);
    }
    __syncthreads();
    int l15 = lane & 15, lh = lane >> 4;
    short8 a[4], b[4];
    #pragma unroll
    for (int i = 0; i < 4; i++)
      a[i] = *(const short8*)(At + (wm*64 + i*16 + l15)*32 + lh*8);
    #pragma unroll
    for (int j = 0; j < 4; j++)
      b[j] = *(const short8*)(Bt + (wn*64 + j*16 + l15)*32 + lh*8);
    #pragma unroll
    for (int i = 0; i < 4; i++)
      #pragma unroll
      for (int j = 0; j < 4; j++)
        acc[i][j] = __builtin_amdgcn_mfma_f32_16x16x32_bf16(a[i], b[j], acc[i][j], 0, 0, 0);
    __syncthreads();
  }
  int l15 = lane & 15, lh = lane >> 4;
  #pragma unroll
  for (int j = 0; j < 4; j++) {
    int col = colbase + wn*64 + j*16 + l15;
    float bs = bsum[col];
    #pragma unroll
    for (int i = 0; i < 4; i++) {
      int row0 = rowbase + wm*64 + i*16 + lh*4;
      #pragma unroll
      for (int r = 0; r < 4; r++)
        y[(long)(row0 + r)*DD + col] = acc[i][j][r] + bs;
    }
  }
}

extern "C" void kernel_launch(void* const* d_in, const int* in_sizes, int n_in,
                              void* d_out, int out_size, void* d_ws, size_t ws_size,
                              hipStream_t stream) {
  (void)in_sizes; (void)n_in; (void)out_size; (void)ws_size;
  const float* x       = (const float*)d_in[0];
  const float* a_logit = (const float*)d_in[1];
  const float* U       = (const float*)d_in[2];
  const float* V       = (const float*)d_in[3];
  const float* W_in    = (const float*)d_in[4];
  const float* b_in    = (const float*)d_in[5];
  const float* W_gate  = (const float*)d_in[6];
  const float* b_gate  = (const float*)d_in[7];
  const float* W_out   = (const float*)d_in[8];
  const float* b_out   = (const float*)d_in[9];
  const float* W_skip  = (const float*)d_in[10];
  const float* b_skip  = (const float*)d_in[11];

  char* ws = (char*)d_ws;
  u16*   Xaug = (u16*)(ws + 0);            // 52,428,800 B
  u16*   Waug = (u16*)(ws + 52428800);     //  1,228,800 B
  u16*   WinG = (u16*)(ws + 53657600);     //     49,152 B
  float* gu_T = (float*)(ws + 53706752);   //  2,097,152 B
  float* Mw   = (float*)(ws + 55803904);   //      1,024 B
  float* MCw  = (float*)(ws + 55804928);   //      1,024 B
  float* cend = (float*)(ws + 55805952);   //     32,768 B
  float* Hst  = (float*)(ws + 55838720);   //     32,768 B
  float* bsum = (float*)(ws + 55871488);   //      3,072 B
  float* y    = (float*)d_out;

  hipLaunchKernelGGL(k_prep,        dim3(1),       dim3(256), 0, stream,
                     a_logit, U, V, b_out, b_skip, Mw, MCw, bsum);
  hipLaunchKernelGGL(k_weights,     dim3(800),     dim3(256), 0, stream,
                     W_skip, W_out, W_in, W_gate, Waug, WinG);
  hipLaunchKernelGGL(k_convert,     dim3(MROWS/4), dim3(256), 0, stream, x, Xaug);
  hipLaunchKernelGGL(k_gu,          dim3(256),     dim3(256), 0, stream,
                     Xaug, WinG, b_in, b_gate, gu_T);
  hipLaunchKernelGGL(k_scan_local,  dim3(128),     dim3(64),  0, stream, gu_T, Mw, cend);
  hipLaunchKernelGGL(k_scan_prefix, dim3(1),       dim3(256), 0, stream, cend, MCw, Hst);
  hipLaunchKernelGGL(k_scan_final,  dim3(128),     dim3(64),  0, stream, gu_T, Mw, Hst, Xaug);
  hipLaunchKernelGGL(k_out,         dim3(1536),    dim3(256), 0, stream,
                     Xaug, Waug, bsum, y);
}

// Round 5
// 330.372 us; speedup vs baseline: 1.0282x; 1.0115x over previous
//
#include <hip/hip_runtime.h>
#include <hip/hip_bf16.h>
#include <math.h>

#define BB 8
#define LL 4096
#define DD 768
#define NN 16
#define RR 8
#define MROWS (BB*LL)       // 32768 rows
#define KAUG 800            // 768 (x) + 16 (hs) + 16 (zero pad)
#define CCH 64              // chunk length for scan
#define NCH (LL/CCH)        // 64 chunks per batch

typedef unsigned int u32;
typedef unsigned short u16;
typedef __attribute__((ext_vector_type(8))) short short8;
typedef __attribute__((ext_vector_type(4))) float f32x4;
typedef __attribute__((ext_vector_type(4))) unsigned short us4;
typedef __attribute__((ext_vector_type(4))) u32 u32x4;

__device__ __forceinline__ u16 f2bf(float f) {
  u32 u = __float_as_uint(f);
  u32 r = (u + 0x7fffu + ((u >> 16) & 1u)) >> 16;  // RNE
  return (u16)r;
}

// packed fp32x2 -> bf16x2 (low = a), RNE via HIP intrinsic
__device__ __forceinline__ u32 pk2bf(float a, float b) {
  __hip_bfloat162 h = __float22bfloat162_rn(make_float2(a, b));
  return *reinterpret_cast<u32*>(&h);
}

__device__ __forceinline__ void gload_lds16(const void* g, void* l) {
  __builtin_amdgcn_global_load_lds(
      (const __attribute__((address_space(1))) u32*)g,
      (__attribute__((address_space(3))) u32*)l, 16, 0, 0);
}

// ---------------- K0a: M = diag(sigmoid(a)) + V U^T ; MC = M^64 ; bsum ----
__global__ void k_prep(const float* __restrict__ a_logit, const float* __restrict__ U,
                       const float* __restrict__ V, const float* __restrict__ b_out,
                       const float* __restrict__ b_skip,
                       float* __restrict__ Mw, float* __restrict__ MCw,
                       float* __restrict__ bsum) {
  __shared__ float cur[256];
  __shared__ float nxt[256];
  int t = threadIdx.x;
  int m = t >> 4, n = t & 15;
  float s = 0.f;
  #pragma unroll
  for (int r = 0; r < RR; r++) s += V[m*RR+r] * U[n*RR+r];
  if (m == n) s += 1.f / (1.f + expf(-a_logit[n]));
  cur[t] = s;
  Mw[t] = s;
  __syncthreads();
  for (int it = 0; it < 6; ++it) {
    float acc = 0.f;
    #pragma unroll
    for (int k = 0; k < 16; k++) acc += cur[m*16+k] * cur[k*16+n];
    nxt[t] = acc;
    __syncthreads();
    cur[t] = nxt[t];
    __syncthreads();
  }
  MCw[t] = cur[t];
  for (int d = t; d < DD; d += 256) bsum[d] = b_out[d] + b_skip[d];
}

// ---------------- K0b: Waug = [W_skip | W_out | 0] bf16 ; WinG = [W_in;W_gate] bf16
__global__ void k_weights(const float* __restrict__ W_skip, const float* __restrict__ W_out,
                          const float* __restrict__ W_in, const float* __restrict__ W_gate,
                          u16* __restrict__ Waug, u16* __restrict__ WinG) {
  int bid = blockIdx.x;
  int t = threadIdx.x;
  if (bid < DD) {
    int d = bid;
    for (int c = t; c < KAUG; c += 256) {
      float v;
      if (c < DD)           v = W_skip[d*DD + c];
      else if (c < DD+NN)   v = W_out[d*NN + (c-DD)];
      else                  v = 0.f;
      Waug[d*KAUG + c] = f2bf(v);
    }
  } else {
    int r = bid - DD;  // 0..31
    const float* Wsrc = (r < NN) ? (W_in + r*DD) : (W_gate + (r-NN)*DD);
    for (int c = t; c < DD; c += 256) WinG[r*DD + c] = f2bf(Wsrc[c]);
  }
}

// ---------------- K2: gu = sigmoid(x@Wg^T+bg)*(x@Wi^T+bi) ; A reg-staged from x fp32
__global__ __launch_bounds__(256) void k_gu(const float* __restrict__ x,
                                            const u16* __restrict__ WinG,
                                            const float* __restrict__ b_in,
                                            const float* __restrict__ b_gate,
                                            float* __restrict__ gu_T) {
  __shared__ u16 At[128*32];
  __shared__ u16 Bt[32*32];
  int tid = threadIdx.x;
  int wave = tid >> 6, lane = tid & 63;
  int rowbase = blockIdx.x * 128;
  int r = tid >> 1, ch = tid & 1;
  const float* xrow = x + (long)(rowbase + r)*DD + ch*16;
  f32x4 acc[2][2] = {};
  for (int it = 0; it < DD/32; ++it) {
    int k0 = it * 32;
    // A: global fp32 -> reg -> bf16 -> LDS
    {
      const float4* xp = (const float4*)(xrow + k0);
      float4 f0 = xp[0], f1 = xp[1], f2 = xp[2], f3 = xp[3];
      u32x4 lo, hi;
      lo.x = pk2bf(f0.x,f0.y); lo.y = pk2bf(f0.z,f0.w);
      lo.z = pk2bf(f1.x,f1.y); lo.w = pk2bf(f1.z,f1.w);
      hi.x = pk2bf(f2.x,f2.y); hi.y = pk2bf(f2.z,f2.w);
      hi.z = pk2bf(f3.x,f3.y); hi.w = pk2bf(f3.z,f3.w);
      *(u32x4*)(At + r*32 + ch*16)     = lo;
      *(u32x4*)(At + r*32 + ch*16 + 8) = hi;
    }
    if (tid < 128) {
      int br = tid >> 2, co = tid & 3;
      gload_lds16(WinG + br*DD + k0 + co*8, Bt + tid*8);
    }
    __syncthreads();
    int l15 = lane & 15, lh = lane >> 4;
    short8 a[2], b[2];
    #pragma unroll
    for (int i = 0; i < 2; i++)
      a[i] = *(const short8*)(At + (wave*32 + i*16 + l15)*32 + lh*8);
    #pragma unroll
    for (int j = 0; j < 2; j++)
      b[j] = *(const short8*)(Bt + (j*16 + l15)*32 + lh*8);
    #pragma unroll
    for (int i = 0; i < 2; i++)
      #pragma unroll
      for (int j = 0; j < 2; j++)
        acc[i][j] = __builtin_amdgcn_mfma_f32_16x16x32_bf16(a[i], b[j], acc[i][j], 0, 0, 0);
    __syncthreads();
  }
  int l15 = lane & 15, lh = lane >> 4;
  float bi = b_in[l15], bg = b_gate[l15];
  #pragma unroll
  for (int i = 0; i < 2; i++) {
    int row0 = rowbase + wave*32 + i*16 + lh*4;   // 4 consecutive rows (same b)
    int b = row0 >> 12;
    int t0 = row0 & 4095;
    float4 o;
    {
      float u0 = acc[i][0][0] + bi, u1 = acc[i][0][1] + bi;
      float u2 = acc[i][0][2] + bi, u3 = acc[i][0][3] + bi;
      float g0 = 1.f/(1.f+__expf(-(acc[i][1][0]+bg)));
      float g1 = 1.f/(1.f+__expf(-(acc[i][1][1]+bg)));
      float g2 = 1.f/(1.f+__expf(-(acc[i][1][2]+bg)));
      float g3 = 1.f/(1.f+__expf(-(acc[i][1][3]+bg)));
      o.x = g0*u0; o.y = g1*u1; o.z = g2*u2; o.w = g3*u3;
    }
    *(float4*)(gu_T + ((long)(b*16 + l15) << 12) + t0) = o;
  }
}

// ---------------- K4: per-chunk local scan from zero -> cend
__global__ void k_scan_local(const float* __restrict__ gu_T, const float* __restrict__ Mw,
                             float* __restrict__ cend) {
  int lane = threadIdx.x & 63;
  int grp = lane >> 4, n = lane & 15;
  int cid = blockIdx.x*4 + grp;      // 0..511
  int b = cid >> 6, k = cid & 63;
  float Mcol[16];
  #pragma unroll
  for (int m = 0; m < 16; m++) Mcol[m] = Mw[m*16 + n];
  const float4* g4 = (const float4*)(gu_T + ((long)(b*16 + n) << 12) + k*CCH);
  float gv[CCH];
  #pragma unroll
  for (int q = 0; q < CCH/4; q++) {
    float4 v = g4[q];
    gv[q*4+0]=v.x; gv[q*4+1]=v.y; gv[q*4+2]=v.z; gv[q*4+3]=v.w;
  }
  float h = 0.f;
  #pragma unroll
  for (int t = 0; t < CCH; t++) {
    float hn = gv[t];
    #pragma unroll
    for (int m = 0; m < 16; m++) hn += __shfl(h, m, 16) * Mcol[m];
    h = hn;
  }
  cend[(b*NCH + k)*NN + n] = h;
}

// ---------------- K5: chunk prefix (LDS-staged)
__global__ void k_scan_prefix(const float* __restrict__ cend, const float* __restrict__ MCw,
                              float* __restrict__ Hstart) {
  __shared__ float s[BB*NCH*NN];   // 8192 floats = 32 KB
  int t = threadIdx.x;             // 256 threads
  for (int i = t; i < BB*NCH*NN; i += 256) s[i] = cend[i];
  __syncthreads();
  if (t < 128) {
    int b = t >> 4, n = t & 15;
    float Mcol[16];
    #pragma unroll
    for (int m = 0; m < 16; m++) Mcol[m] = MCw[m*16 + n];
    float h = 0.f;
    for (int k = 0; k < NCH; k++) {
      Hstart[(b*NCH + k)*NN + n] = h;
      float hn = s[(b*NCH + k)*NN + n];
      #pragma unroll
      for (int m = 0; m < 16; m++) hn += __shfl(h, m, 16) * Mcol[m];
      h = hn;
    }
  }
}

// ---------------- K6: chunk final scan -> hs bf16 [32768][16]
__global__ void k_scan_final(const float* __restrict__ gu_T, const float* __restrict__ Mw,
                             const float* __restrict__ Hstart, u16* __restrict__ hs) {
  int lane = threadIdx.x & 63;
  int grp = lane >> 4, n = lane & 15;
  int cid = blockIdx.x*4 + grp;
  int b = cid >> 6, k = cid & 63;
  float Mcol[16];
  #pragma unroll
  for (int m = 0; m < 16; m++) Mcol[m] = Mw[m*16 + n];
  const float4* g4 = (const float4*)(gu_T + ((long)(b*16 + n) << 12) + k*CCH);
  float gv[CCH];
  #pragma unroll
  for (int q = 0; q < CCH/4; q++) {
    float4 v = g4[q];
    gv[q*4+0]=v.x; gv[q*4+1]=v.y; gv[q*4+2]=v.z; gv[q*4+3]=v.w;
  }
  float h = Hstart[(b*NCH + k)*NN + n];
  u16* hp = hs + ((long)(b*LL) + k*CCH)*NN + n;
  #pragma unroll
  for (int t = 0; t < CCH; t++) {
    float hn = gv[t];
    #pragma unroll
    for (int m = 0; m < 16; m++) hn += __shfl(h, m, 16) * Mcol[m];
    h = hn;
    hp[(long)t*NN] = f2bf(h);
  }
}

// ---------------- K7: y = [x|hs|0] @ Waug^T + bsum   (M=32768, N=768, K=800)
// A-tile reg-staged from x fp32 (iters 0..23) and hs bf16 (iter 24)
__global__ __launch_bounds__(256) void k_out(const float* __restrict__ x,
                                             const u16* __restrict__ hs,
                                             const u16* __restrict__ Waug,
                                             const float* __restrict__ bsum,
                                             float* __restrict__ y) {
  __shared__ u16 At[128*32];
  __shared__ u16 Bt[128*32];
  int tid = threadIdx.x;
  int wave = tid >> 6, lane = tid & 63;
  int wm = wave >> 1, wn = wave & 1;
  int rowbase = blockIdx.x * 128;
  int colbase = blockIdx.y * 128;
  int r = tid >> 1, ch = tid & 1;
  const float* xrow = x + (long)(rowbase + r)*DD + ch*16;
  f32x4 acc[4][4] = {};
  for (int it = 0; it < 25; ++it) {
    int k0 = it * 32;
    // B staging via global_load_lds (Waug bf16, includes zero pad cols)
    #pragma unroll
    for (int p = 0; p < 2; p++) {
      int cc = tid + p*256;
      int br = cc >> 2, bco = cc & 3;
      gload_lds16(Waug + (long)(colbase + br)*KAUG + k0 + bco*8, Bt + cc*8);
    }
    // A staging: reg-staged
    if (it < 24) {
      const float4* xp = (const float4*)(xrow + k0);
      float4 f0 = xp[0], f1 = xp[1], f2 = xp[2], f3 = xp[3];
      u32x4 lo, hi;
      lo.x = pk2bf(f0.x,f0.y); lo.y = pk2bf(f0.z,f0.w);
      lo.z = pk2bf(f1.x,f1.y); lo.w = pk2bf(f1.z,f1.w);
      hi.x = pk2bf(f2.x,f2.y); hi.y = pk2bf(f2.z,f2.w);
      hi.z = pk2bf(f3.x,f3.y); hi.w = pk2bf(f3.z,f3.w);
      *(u32x4*)(At + r*32 + ch*16)     = lo;
      *(u32x4*)(At + r*32 + ch*16 + 8) = hi;
    } else {
      if (ch == 0) {               // cols 0..15 of this K-tile = hs row
        const u32x4* hp = (const u32x4*)(hs + (long)(rowbase + r)*NN);
        *(u32x4*)(At + r*32)     = hp[0];
        *(u32x4*)(At + r*32 + 8) = hp[1];
      } else {                     // cols 16..31 = zero (match Waug zero pad)
        u32x4 z = (u32x4)0;
        *(u32x4*)(At + r*32 + 16) = z;
        *(u32x4*)(At + r*32 + 24) = z;
      }
    }
    __syncthreads();
    int l15 = lane & 15, lh = lane >> 4;
    short8 a[4], b[4];
    #pragma unroll
    for (int i = 0; i < 4; i++)
      a[i] = *(const short8*)(At + (wm*64 + i*16 + l15)*32 + lh*8);
    #pragma unroll
    for (int j = 0; j < 4; j++)
      b[j] = *(const short8*)(Bt + (wn*64 + j*16 + l15)*32 + lh*8);
    #pragma unroll
    for (int i = 0; i < 4; i++)
      #pragma unroll
      for (int j = 0; j < 4; j++)
        acc[i][j] = __builtin_amdgcn_mfma_f32_16x16x32_bf16(a[i], b[j], acc[i][j], 0, 0, 0);
    __syncthreads();
  }
  int l15 = lane & 15, lh = lane >> 4;
  #pragma unroll
  for (int j = 0; j < 4; j++) {
    int col = colbase + wn*64 + j*16 + l15;
    float bs = bsum[col];
    #pragma unroll
    for (int i = 0; i < 4; i++) {
      int row0 = rowbase + wm*64 + i*16 + lh*4;
      #pragma unroll
      for (int rr = 0; rr < 4; rr++)
        y[(long)(row0 + rr)*DD + col] = acc[i][j][rr] + bs;
    }
  }
}

extern "C" void kernel_launch(void* const* d_in, const int* in_sizes, int n_in,
                              void* d_out, int out_size, void* d_ws, size_t ws_size,
                              hipStream_t stream) {
  (void)in_sizes; (void)n_in; (void)out_size; (void)ws_size;
  const float* x       = (const float*)d_in[0];
  const float* a_logit = (const float*)d_in[1];
  const float* U       = (const float*)d_in[2];
  const float* V       = (const float*)d_in[3];
  const float* W_in    = (const float*)d_in[4];
  const float* b_in    = (const float*)d_in[5];
  const float* W_gate  = (const float*)d_in[6];
  const float* b_gate  = (const float*)d_in[7];
  const float* W_out   = (const float*)d_in[8];
  const float* b_out   = (const float*)d_in[9];
  const float* W_skip  = (const float*)d_in[10];
  const float* b_skip  = (const float*)d_in[11];

  char* ws = (char*)d_ws;
  u16*   Waug = (u16*)(ws + 0);            // 1,228,800 B
  u16*   WinG = (u16*)(ws + 1228800);      //    49,152 B
  float* gu_T = (float*)(ws + 1277952);    // 2,097,152 B
  u16*   hs   = (u16*)(ws + 3375104);      // 1,048,576 B
  float* Mw   = (float*)(ws + 4423680);    //     1,024 B
  float* MCw  = (float*)(ws + 4424704);    //     1,024 B
  float* cend = (float*)(ws + 4425728);    //    32,768 B
  float* Hst  = (float*)(ws + 4458496);    //    32,768 B
  float* bsum = (float*)(ws + 4491264);    //     3,072 B
  float* y    = (float*)d_out;

  hipLaunchKernelGGL(k_prep,        dim3(1),      dim3(256), 0, stream,
                     a_logit, U, V, b_out, b_skip, Mw, MCw, bsum);
  hipLaunchKernelGGL(k_weights,     dim3(800),    dim3(256), 0, stream,
                     W_skip, W_out, W_in, W_gate, Waug, WinG);
  hipLaunchKernelGGL(k_gu,          dim3(256),    dim3(256), 0, stream,
                     x, WinG, b_in, b_gate, gu_T);
  hipLaunchKernelGGL(k_scan_local,  dim3(128),    dim3(64),  0, stream, gu_T, Mw, cend);
  hipLaunchKernelGGL(k_scan_prefix, dim3(1),      dim3(256), 0, stream, cend, MCw, Hst);
  hipLaunchKernelGGL(k_scan_final,  dim3(128),    dim3(64),  0, stream, gu_T, Mw, Hst, hs);
  hipLaunchKernelGGL(k_out,         dim3(256, 6), dim3(256), 0, stream,
                     x, hs, Waug, bsum, y);
}